// Round 1
// baseline (6295.339 us; speedup 1.0000x reference)
//
#include <hip/hip_runtime.h>
#include <hip/hip_fp16.h>

#define SEQT 2048
#define HID  256
#define NB   64

typedef _Float16 h2 __attribute__((ext_vector_type(2)));

__device__ __forceinline__ unsigned int pkrtz(float a, float b) {
  return __builtin_bit_cast(unsigned int, __builtin_amdgcn_cvt_pkrtz(a, b));
}
__device__ __forceinline__ float fdot2u(unsigned int a, unsigned int b, float c) {
  return __builtin_amdgcn_fdot2(__builtin_bit_cast(h2, a),
                                __builtin_bit_cast(h2, b), c, false);
}
__device__ __forceinline__ float sigf(float x) { return 1.f / (1.f + __expf(-x)); }
__device__ __forceinline__ float tanhf_fast(float x) {
  float e = __expf(-2.f * fabsf(x));
  float r = (1.f - e) / (1.f + e);
  return copysignf(r, x);
}

// One workgroup per batch element. Thread t owns gate rows {t, 256+t, 512+t, 768+t}
// (= i,f,g,o for h-index t) and the c[t]/h[t] state. Weights f16-packed:
// k in [0,192) in VGPRs (4*96 dwords), k in [192,256) in LDS (XOR-swizzled b128 blocks).
// h broadcast via 512B double-buffered LDS (uniform-address b128 reads). 1 barrier/step.
__global__ __launch_bounds__(256, 1) void lstm_main(
    const float* __restrict__ x, const float* __restrict__ Wih,
    const float* __restrict__ Whh, const float* __restrict__ bih,
    const float* __restrict__ bhh, float* __restrict__ out,
    __half* __restrict__ hist)
{
  extern __shared__ unsigned int lds[];
  unsigned int* wlds = lds;                 // [4][256][32] dwords = 128KB
  unsigned int* hb   = lds + 4 * 256 * 32;  // [2][128] dwords (f16x2 h, double buffered)

  const int t = threadIdx.x;
  const int b = blockIdx.x;

  hb[t] = 0u;  // zeroes both h buffers (256 dwords)

  float bias[4], wih[4];
#pragma unroll
  for (int q = 0; q < 4; ++q) {
    int r = q * 256 + t;
    bias[q] = bih[r] + bhh[r];
    wih[q]  = Wih[r];
  }

  // ---- pack weights: f32 -> f16x2 ----
  unsigned int wv[4][96];
#pragma unroll
  for (int q = 0; q < 4; ++q) {
    const float4* row = (const float4*)(Whh + (size_t)(q * 256 + t) * 256);
#pragma unroll
    for (int j = 0; j < 48; ++j) {          // k in [0,192)
      float4 f = row[j];
      wv[q][2 * j]     = pkrtz(f.x, f.y);
      wv[q][2 * j + 1] = pkrtz(f.z, f.w);
    }
#pragma unroll
    for (int blk = 0; blk < 8; ++blk) {     // k in [192,256) -> LDS, swizzled
      float4 f0 = row[48 + 2 * blk];
      float4 f1 = row[49 + 2 * blk];
      uint4 w;
      w.x = pkrtz(f0.x, f0.y);
      w.y = pkrtz(f0.z, f0.w);
      w.z = pkrtz(f1.x, f1.y);
      w.w = pkrtz(f1.z, f1.w);
      *(uint4*)(wlds + ((q * 256 + t) * 32 + ((blk ^ (t & 7)) * 4))) = w;
    }
  }
  __syncthreads();

  const float* xb = x + (size_t)b * SEQT;
  __half* hrow = hist + (size_t)b * SEQT * HID + t;
  float c = 0.f, h = 0.f;
  float xv = xb[0];
  float a[4];

  for (int step = 0; step < SEQT; ++step) {
    const unsigned int* hp = hb + (step & 1) * 128;
    unsigned int*       hn = hb + (((step & 1) ^ 1) * 128);
    float xnext = xb[(step + 1) & (SEQT - 1)];   // wraps harmlessly at last step

#pragma unroll
    for (int q = 0; q < 4; ++q) a[q] = bias[q] + wih[q] * xv;

    // VGPR-resident weights: k in [0,192)
#pragma unroll
    for (int c4 = 0; c4 < 24; ++c4) {
      uint4 hc = *(const uint4*)(hp + 4 * c4);   // broadcast read
#pragma unroll
      for (int q = 0; q < 4; ++q) {
        a[q] = fdot2u(wv[q][4 * c4 + 0], hc.x, a[q]);
        a[q] = fdot2u(wv[q][4 * c4 + 1], hc.y, a[q]);
        a[q] = fdot2u(wv[q][4 * c4 + 2], hc.z, a[q]);
        a[q] = fdot2u(wv[q][4 * c4 + 3], hc.w, a[q]);
      }
    }
    // LDS-resident weights: k in [192,256)
#pragma unroll
    for (int blk = 0; blk < 8; ++blk) {
      uint4 hc = *(const uint4*)(hp + 96 + 4 * blk);
#pragma unroll
      for (int q = 0; q < 4; ++q) {
        uint4 w = *(const uint4*)(wlds + ((q * 256 + t) * 32 + ((blk ^ (t & 7)) * 4)));
        a[q] = fdot2u(w.x, hc.x, a[q]);
        a[q] = fdot2u(w.y, hc.y, a[q]);
        a[q] = fdot2u(w.z, hc.z, a[q]);
        a[q] = fdot2u(w.w, hc.w, a[q]);
      }
    }

    float gi = sigf(a[0]);
    float gf = sigf(a[1]);
    float gg = tanhf_fast(a[2]);
    float go = sigf(a[3]);
    c = gf * c + gi * gg;
    h = go * tanhf_fast(c);

    __half h16 = __float2half(h);
    ((__half*)hn)[t] = h16;                 // next step's h broadcast buffer
    hrow[(size_t)step * HID] = h16;         // history for the linear head
    xv = xnext;
    __syncthreads();
  }

  out[NB * SEQT + b * HID + t]            = h;  // h_n
  out[NB * SEQT + NB * HID + b * HID + t] = c;  // c_n
}

// y[b,t] = Wfc . h[b,t,:] + bfc  — one wave per output, coalesced 8B/lane loads.
__global__ __launch_bounds__(256) void lstm_head(
    const __half* __restrict__ hist, const float* __restrict__ Wfc,
    const float* __restrict__ bfc, float* __restrict__ y)
{
  int gw   = (blockIdx.x * 256 + threadIdx.x) >> 6;  // global wave id = output idx
  int lane = threadIdx.x & 63;
  uint2 hv = ((const uint2*)(hist + (size_t)gw * HID))[lane];
  float4 w = ((const float4*)Wfc)[lane];
  h2 p0 = __builtin_bit_cast(h2, hv.x);
  h2 p1 = __builtin_bit_cast(h2, hv.y);
  float s = (float)p0.x * w.x + (float)p0.y * w.y +
            (float)p1.x * w.z + (float)p1.y * w.w;
#pragma unroll
  for (int m = 32; m; m >>= 1) s += __shfl_xor(s, m, 64);
  if (lane == 0) y[gw] = s + bfc[0];
}

extern "C" void kernel_launch(void* const* d_in, const int* in_sizes, int n_in,
                              void* d_out, int out_size, void* d_ws, size_t ws_size,
                              hipStream_t stream)
{
  const float* x   = (const float*)d_in[0];
  const float* Wih = (const float*)d_in[1];
  const float* Whh = (const float*)d_in[2];
  const float* bih = (const float*)d_in[3];
  const float* bhh = (const float*)d_in[4];
  const float* Wfc = (const float*)d_in[5];
  const float* bfc = (const float*)d_in[6];
  float* out      = (float*)d_out;
  __half* hist    = (__half*)d_ws;   // needs 64*2048*256*2 = 64 MiB

  (void)in_sizes; (void)n_in; (void)out_size; (void)ws_size;

  hipFuncSetAttribute((const void*)lstm_main,
                      hipFuncAttributeMaxDynamicSharedMemorySize, 132096);
  lstm_main<<<dim3(NB), dim3(256), 132096, stream>>>(x, Wih, Whh, bih, bhh, out, hist);
  lstm_head<<<dim3((NB * SEQT) / 4), dim3(256), 0, stream>>>(hist, Wfc, bfc, out);
}

// Round 2
// 3658.329 us; speedup vs baseline: 1.7208x; 1.7208x over previous
//
#include <hip/hip_runtime.h>
#include <hip/hip_fp16.h>

#define SEQT 2048
#define HID  256
#define NB   64
#define PADW 68   // dwords per thread in LDS weight region (64 used + 4 pad; 272B stride keeps 16B align + bank spread)

typedef _Float16 h2 __attribute__((ext_vector_type(2)));

__device__ __forceinline__ unsigned int pkrtz(float a, float b) {
  return __builtin_bit_cast(unsigned int, __builtin_amdgcn_cvt_pkrtz(a, b));
}
__device__ __forceinline__ float fdot2u(unsigned int a, unsigned int b, float c) {
  return __builtin_amdgcn_fdot2(__builtin_bit_cast(h2, a),
                                __builtin_bit_cast(h2, b), c, false);
}
__device__ __forceinline__ float sigf(float x) { return 1.f / (1.f + __expf(-x)); }
__device__ __forceinline__ float tanhf_fast(float x) {
  float e = __expf(-2.f * fabsf(x));
  float r = (1.f - e) / (1.f + e);
  return copysignf(r, x);
}

// One workgroup (512 thr = 8 waves) per batch element. Thread t owns gate rows
// {t, 512+t}: t<256 -> (i,g) of h-index t; t>=256 -> (f,o) of h-index t-256.
// Weights f16-packed: k in [0,192) in VGPRs (192 dwords), k in [192,256) in LDS.
// h broadcast via 512B double-buffered LDS; P=sig(i)*tanh(g) exchanged via LDS.
// 2 barriers/step.
__global__ __launch_bounds__(512, 2) void lstm_main(
    const float* __restrict__ x, const float* __restrict__ Wih,
    const float* __restrict__ Whh, const float* __restrict__ bih,
    const float* __restrict__ bhh, float* __restrict__ out,
    __half* __restrict__ hist)
{
  extern __shared__ unsigned int lds[];
  unsigned int* wlds = lds;                      // [512][PADW] dwords
  unsigned int* hb   = lds + 512 * PADW;         // [2][128] dwords (f16x2 h, double buffered)
  float*        Pl   = (float*)(lds + 512 * PADW + 256);  // [256] f32

  const int t = threadIdx.x;
  const int b = blockIdx.x;

  if (t < 256) hb[t] = 0u;                       // zero both h buffers

  const int rowA = t;        // i-row (t<256) or f-row (t>=256)
  const int rowB = 512 + t;  // g-row (t<256) or o-row (t>=256)

  float biasA = bih[rowA] + bhh[rowA];
  float biasB = bih[rowB] + bhh[rowB];
  float wihA  = Wih[rowA];
  float wihB  = Wih[rowB];

  // ---- pack weights: f32 -> f16x2 ----
  unsigned int wv[2][96];
  const float4* rA = (const float4*)(Whh + (size_t)rowA * HID);
  const float4* rB = (const float4*)(Whh + (size_t)rowB * HID);
#pragma unroll
  for (int j = 0; j < 48; ++j) {                 // k in [0,192): VGPR-resident
    float4 f = rA[j];
    wv[0][2 * j]     = pkrtz(f.x, f.y);
    wv[0][2 * j + 1] = pkrtz(f.z, f.w);
  }
#pragma unroll
  for (int j = 0; j < 48; ++j) {
    float4 f = rB[j];
    wv[1][2 * j]     = pkrtz(f.x, f.y);
    wv[1][2 * j + 1] = pkrtz(f.z, f.w);
  }
  unsigned int* wbase = wlds + t * PADW;
#pragma unroll
  for (int r = 0; r < 2; ++r) {                  // k in [192,256): LDS-resident
    const float4* row = r ? rB : rA;
#pragma unroll
    for (int jj = 0; jj < 8; ++jj) {
      float4 f0 = row[48 + 2 * jj];
      float4 f1 = row[49 + 2 * jj];
      uint4 w;
      w.x = pkrtz(f0.x, f0.y);
      w.y = pkrtz(f0.z, f0.w);
      w.z = pkrtz(f1.x, f1.y);
      w.w = pkrtz(f1.z, f1.w);
      *(uint4*)(wbase + (r * 8 + jj) * 4) = w;
    }
  }
  __syncthreads();

  const float* xb = x + (size_t)b * SEQT;
  const int jh = (t >= 256) ? (t - 256) : 0;     // h-index this (high) thread owns
  __half* hrow = hist + (size_t)b * SEQT * HID + jh;
  float c = 0.f, h = 0.f;
  float xv = xb[0];

  for (int step = 0; step < SEQT; ++step) {
    const uint4* hp = (const uint4*)(hb + (step & 1) * 128);
    __half*      hn = (__half*)(hb + (((step & 1) ^ 1) * 128));
    float xnext = xb[(step + 1) & (SEQT - 1)];   // wraps harmlessly at last step

    float aA0 = biasA + wihA * xv, aA1 = 0.f;
    float aB0 = biasB + wihB * xv, aB1 = 0.f;

    // VGPR-resident weights: k in [0,192)
#pragma unroll
    for (int j = 0; j < 24; ++j) {
      uint4 hc = hp[j];                          // uniform-address broadcast read
      if (j & 1) {
        aA1 = fdot2u(wv[0][4 * j + 0], hc.x, aA1);
        aA1 = fdot2u(wv[0][4 * j + 1], hc.y, aA1);
        aA1 = fdot2u(wv[0][4 * j + 2], hc.z, aA1);
        aA1 = fdot2u(wv[0][4 * j + 3], hc.w, aA1);
        aB1 = fdot2u(wv[1][4 * j + 0], hc.x, aB1);
        aB1 = fdot2u(wv[1][4 * j + 1], hc.y, aB1);
        aB1 = fdot2u(wv[1][4 * j + 2], hc.z, aB1);
        aB1 = fdot2u(wv[1][4 * j + 3], hc.w, aB1);
      } else {
        aA0 = fdot2u(wv[0][4 * j + 0], hc.x, aA0);
        aA0 = fdot2u(wv[0][4 * j + 1], hc.y, aA0);
        aA0 = fdot2u(wv[0][4 * j + 2], hc.z, aA0);
        aA0 = fdot2u(wv[0][4 * j + 3], hc.w, aA0);
        aB0 = fdot2u(wv[1][4 * j + 0], hc.x, aB0);
        aB0 = fdot2u(wv[1][4 * j + 1], hc.y, aB0);
        aB0 = fdot2u(wv[1][4 * j + 2], hc.z, aB0);
        aB0 = fdot2u(wv[1][4 * j + 3], hc.w, aB0);
      }
    }
    // LDS-resident weights: k in [192,256)  (immediate-offset ds_read_b128, bank-spread by PADW stride)
#pragma unroll
    for (int jj = 0; jj < 8; ++jj) {
      uint4 hc = hp[24 + jj];
      uint4 wA = *(const uint4*)(wbase + jj * 4);
      uint4 wB = *(const uint4*)(wbase + (8 + jj) * 4);
      if (jj & 1) {
        aA1 = fdot2u(wA.x, hc.x, aA1);
        aA1 = fdot2u(wA.y, hc.y, aA1);
        aA1 = fdot2u(wA.z, hc.z, aA1);
        aA1 = fdot2u(wA.w, hc.w, aA1);
        aB1 = fdot2u(wB.x, hc.x, aB1);
        aB1 = fdot2u(wB.y, hc.y, aB1);
        aB1 = fdot2u(wB.z, hc.z, aB1);
        aB1 = fdot2u(wB.w, hc.w, aB1);
      } else {
        aA0 = fdot2u(wA.x, hc.x, aA0);
        aA0 = fdot2u(wA.y, hc.y, aA0);
        aA0 = fdot2u(wA.z, hc.z, aA0);
        aA0 = fdot2u(wA.w, hc.w, aA0);
        aB0 = fdot2u(wB.x, hc.x, aB0);
        aB0 = fdot2u(wB.y, hc.y, aB0);
        aB0 = fdot2u(wB.z, hc.z, aB0);
        aB0 = fdot2u(wB.w, hc.w, aB0);
      }
    }

    float aA = aA0 + aA1;
    float aB = aB0 + aB1;

    if (t < 256) {
      Pl[t] = sigf(aA) * tanhf_fast(aB);         // i * g
    }
    __syncthreads();
    if (t >= 256) {
      float F = sigf(aA);                        // f
      float O = sigf(aB);                        // o
      c = F * c + Pl[t - 256];
      h = O * tanhf_fast(c);
      __half h16 = __float2half(h);
      hn[t - 256] = h16;                         // next step's h broadcast buffer
      hrow[(size_t)step * HID] = h16;            // history for the linear head
    }
    xv = xnext;
    __syncthreads();
  }

  if (t >= 256) {
    int j = t - 256;
    out[NB * SEQT + b * HID + j]            = h;  // h_n
    out[NB * SEQT + NB * HID + b * HID + j] = c;  // c_n
  }
}

// y[b,t] = Wfc . h[b,t,:] + bfc  — one wave per output, coalesced 8B/lane loads.
__global__ __launch_bounds__(256) void lstm_head(
    const __half* __restrict__ hist, const float* __restrict__ Wfc,
    const float* __restrict__ bfc, float* __restrict__ y)
{
  int gw   = (blockIdx.x * 256 + threadIdx.x) >> 6;  // global wave id = output idx
  int lane = threadIdx.x & 63;
  uint2 hv = ((const uint2*)(hist + (size_t)gw * HID))[lane];
  float4 w = ((const float4*)Wfc)[lane];
  h2 p0 = __builtin_bit_cast(h2, hv.x);
  h2 p1 = __builtin_bit_cast(h2, hv.y);
  float s = (float)p0.x * w.x + (float)p0.y * w.y +
            (float)p1.x * w.z + (float)p1.y * w.w;
#pragma unroll
  for (int m = 32; m; m >>= 1) s += __shfl_xor(s, m, 64);
  if (lane == 0) y[gw] = s + bfc[0];
}

extern "C" void kernel_launch(void* const* d_in, const int* in_sizes, int n_in,
                              void* d_out, int out_size, void* d_ws, size_t ws_size,
                              hipStream_t stream)
{
  const float* x   = (const float*)d_in[0];
  const float* Wih = (const float*)d_in[1];
  const float* Whh = (const float*)d_in[2];
  const float* bih = (const float*)d_in[3];
  const float* bhh = (const float*)d_in[4];
  const float* Wfc = (const float*)d_in[5];
  const float* bfc = (const float*)d_in[6];
  float* out      = (float*)d_out;
  __half* hist    = (__half*)d_ws;   // needs 64*2048*256*2 = 64 MiB

  (void)in_sizes; (void)n_in; (void)out_size; (void)ws_size;

  const int ldsBytes = 512 * PADW * 4 + 256 * 4 + 256 * 4;  // 141312
  hipFuncSetAttribute((const void*)lstm_main,
                      hipFuncAttributeMaxDynamicSharedMemorySize, ldsBytes);
  lstm_main<<<dim3(NB), dim3(512), ldsBytes, stream>>>(x, Wih, Whh, bih, bhh, out, hist);
  lstm_head<<<dim3((NB * SEQT) / 4), dim3(256), 0, stream>>>(hist, Wfc, bfc, out);
}

// Round 3
// 3529.282 us; speedup vs baseline: 1.7837x; 1.0366x over previous
//
#include <hip/hip_runtime.h>
#include <hip/hip_fp16.h>

#define SEQT 2048
#define HID  256
#define NB   64
#define PADW 52   // dwords/thread in LDS weight region (48 used + 4 pad; 208B stride: lanes 0-7 cover all 32 banks)

typedef _Float16 h2 __attribute__((ext_vector_type(2)));

__device__ __forceinline__ unsigned int pkrtz(float a, float b) {
  return __builtin_bit_cast(unsigned int, __builtin_amdgcn_cvt_pkrtz(a, b));
}
__device__ __forceinline__ float fdot2u(unsigned int a, unsigned int b, float c) {
  return __builtin_amdgcn_fdot2(__builtin_bit_cast(h2, a),
                                __builtin_bit_cast(h2, b), c, false);
}
__device__ __forceinline__ float sigf(float x) { return 1.f / (1.f + __expf(-x)); }
__device__ __forceinline__ float tanhf_fast(float x) {
  float e = __expf(-2.f * fabsf(x));
  float r = (1.f - e) / (1.f + e);
  return copysignf(r, x);
}

// One workgroup (512 thr = 8 waves) per batch element. Thread t owns gate rows
// {t, 512+t}: t<256 -> (i,g) of h-index t; t>=256 -> (f,o) of h-index t-256.
// Weights f16-packed: k in [0,208) in VGPRs (208 dwords), k in [208,256) in LDS.
// amdgpu_waves_per_eu(2,2) pins 2 waves/SIMD so the allocator uses the full
// 256-arch-VGPR budget instead of splitting 128 VGPR + AGPR spill (R2 failure).
// h broadcast via 512B double-buffered LDS; P=sig(i)*tanh(g) exchanged via LDS.
__global__ __attribute__((amdgpu_flat_work_group_size(512, 512),
                          amdgpu_waves_per_eu(2, 2)))
void lstm_main(
    const float* __restrict__ x, const float* __restrict__ Wih,
    const float* __restrict__ Whh, const float* __restrict__ bih,
    const float* __restrict__ bhh, float* __restrict__ out,
    __half* __restrict__ hist)
{
  extern __shared__ unsigned int lds[];
  unsigned int* wlds = lds;                      // [512][PADW] dwords
  unsigned int* hb   = lds + 512 * PADW;         // [2][128] dwords (f16x2 h, double buffered)
  float*        Pl   = (float*)(lds + 512 * PADW + 256);  // [256] f32

  const int t = threadIdx.x;
  const int b = blockIdx.x;

  if (t < 256) hb[t] = 0u;                       // zero both h buffers

  const int rowA = t;        // i-row (t<256) or f-row (t>=256)
  const int rowB = 512 + t;  // g-row (t<256) or o-row (t>=256)

  float biasA = bih[rowA] + bhh[rowA];
  float biasB = bih[rowB] + bhh[rowB];
  float wihA  = Wih[rowA];
  float wihB  = Wih[rowB];

  // ---- pack weights: f32 -> f16x2 ----
  // VGPR-resident: k in [0,208) -> 52 float4 per row -> 104 dwords per row
  unsigned int wv[2][104];
  const float4* rA = (const float4*)(Whh + (size_t)rowA * HID);
  const float4* rB = (const float4*)(Whh + (size_t)rowB * HID);
#pragma unroll
  for (int j = 0; j < 52; ++j) {
    float4 f = rA[j];
    wv[0][2 * j]     = pkrtz(f.x, f.y);
    wv[0][2 * j + 1] = pkrtz(f.z, f.w);
  }
#pragma unroll
  for (int j = 0; j < 52; ++j) {
    float4 f = rB[j];
    wv[1][2 * j]     = pkrtz(f.x, f.y);
    wv[1][2 * j + 1] = pkrtz(f.z, f.w);
  }
  // LDS-resident: k in [208,256) -> 12 float4 per row -> 6 b128 per row
  unsigned int* wbase = wlds + t * PADW;
#pragma unroll
  for (int r = 0; r < 2; ++r) {
    const float4* row = r ? rB : rA;
#pragma unroll
    for (int jj = 0; jj < 6; ++jj) {
      float4 f0 = row[52 + 2 * jj];
      float4 f1 = row[53 + 2 * jj];
      uint4 w;
      w.x = pkrtz(f0.x, f0.y);
      w.y = pkrtz(f0.z, f0.w);
      w.z = pkrtz(f1.x, f1.y);
      w.w = pkrtz(f1.z, f1.w);
      *(uint4*)(wbase + (r * 6 + jj) * 4) = w;
    }
  }
  __syncthreads();

  const float* xb = x + (size_t)b * SEQT;
  const int jh = (t >= 256) ? (t - 256) : 0;     // h-index this (high) thread owns
  __half* hrow = hist + (size_t)b * SEQT * HID + jh;
  float c = 0.f, h = 0.f;
  float xv = xb[0];

  for (int step = 0; step < SEQT; ++step) {
    const uint4* hp = (const uint4*)(hb + (step & 1) * 128);
    __half*      hn = (__half*)(hb + (((step & 1) ^ 1) * 128));
    float xnext = xb[(step + 1) & (SEQT - 1)];   // wraps harmlessly at last step

    float aA0 = biasA + wihA * xv, aA1 = 0.f;
    float aB0 = biasB + wihB * xv, aB1 = 0.f;

    // VGPR-resident weights: k in [0,208), 26 uniform h b128 reads
#pragma unroll
    for (int j = 0; j < 26; ++j) {
      uint4 hc = hp[j];                          // uniform-address broadcast read
      if (j & 1) {
        aA1 = fdot2u(wv[0][4 * j + 0], hc.x, aA1);
        aA1 = fdot2u(wv[0][4 * j + 1], hc.y, aA1);
        aA1 = fdot2u(wv[0][4 * j + 2], hc.z, aA1);
        aA1 = fdot2u(wv[0][4 * j + 3], hc.w, aA1);
        aB1 = fdot2u(wv[1][4 * j + 0], hc.x, aB1);
        aB1 = fdot2u(wv[1][4 * j + 1], hc.y, aB1);
        aB1 = fdot2u(wv[1][4 * j + 2], hc.z, aB1);
        aB1 = fdot2u(wv[1][4 * j + 3], hc.w, aB1);
      } else {
        aA0 = fdot2u(wv[0][4 * j + 0], hc.x, aA0);
        aA0 = fdot2u(wv[0][4 * j + 1], hc.y, aA0);
        aA0 = fdot2u(wv[0][4 * j + 2], hc.z, aA0);
        aA0 = fdot2u(wv[0][4 * j + 3], hc.w, aA0);
        aB0 = fdot2u(wv[1][4 * j + 0], hc.x, aB0);
        aB0 = fdot2u(wv[1][4 * j + 1], hc.y, aB0);
        aB0 = fdot2u(wv[1][4 * j + 2], hc.z, aB0);
        aB0 = fdot2u(wv[1][4 * j + 3], hc.w, aB0);
      }
    }
    // LDS-resident weights: k in [208,256)  (immediate-offset ds_read_b128)
#pragma unroll
    for (int jj = 0; jj < 6; ++jj) {
      uint4 hc = hp[26 + jj];
      uint4 wA = *(const uint4*)(wbase + jj * 4);
      uint4 wB = *(const uint4*)(wbase + (6 + jj) * 4);
      if (jj & 1) {
        aA1 = fdot2u(wA.x, hc.x, aA1);
        aA1 = fdot2u(wA.y, hc.y, aA1);
        aA1 = fdot2u(wA.z, hc.z, aA1);
        aA1 = fdot2u(wA.w, hc.w, aA1);
        aB1 = fdot2u(wB.x, hc.x, aB1);
        aB1 = fdot2u(wB.y, hc.y, aB1);
        aB1 = fdot2u(wB.z, hc.z, aB1);
        aB1 = fdot2u(wB.w, hc.w, aB1);
      } else {
        aA0 = fdot2u(wA.x, hc.x, aA0);
        aA0 = fdot2u(wA.y, hc.y, aA0);
        aA0 = fdot2u(wA.z, hc.z, aA0);
        aA0 = fdot2u(wA.w, hc.w, aA0);
        aB0 = fdot2u(wB.x, hc.x, aB0);
        aB0 = fdot2u(wB.y, hc.y, aB0);
        aB0 = fdot2u(wB.z, hc.z, aB0);
        aB0 = fdot2u(wB.w, hc.w, aB0);
      }
    }

    float aA = aA0 + aA1;
    float aB = aB0 + aB1;

    if (t < 256) {
      Pl[t] = sigf(aA) * tanhf_fast(aB);         // i * g
    }
    __syncthreads();
    if (t >= 256) {
      float F = sigf(aA);                        // f
      float O = sigf(aB);                        // o
      c = F * c + Pl[t - 256];
      h = O * tanhf_fast(c);
      __half h16 = __float2half(h);
      hn[t - 256] = h16;                         // next step's h broadcast buffer
      hrow[(size_t)step * HID] = h16;            // history for the linear head
    }
    xv = xnext;
    __syncthreads();
  }

  if (t >= 256) {
    int j = t - 256;
    out[NB * SEQT + b * HID + j]            = h;  // h_n
    out[NB * SEQT + NB * HID + b * HID + j] = c;  // c_n
  }
}

// y[b,t] = Wfc . h[b,t,:] + bfc  — one wave per output, coalesced 8B/lane loads.
__global__ __launch_bounds__(256) void lstm_head(
    const __half* __restrict__ hist, const float* __restrict__ Wfc,
    const float* __restrict__ bfc, float* __restrict__ y)
{
  int gw   = (blockIdx.x * 256 + threadIdx.x) >> 6;  // global wave id = output idx
  int lane = threadIdx.x & 63;
  uint2 hv = ((const uint2*)(hist + (size_t)gw * HID))[lane];
  float4 w = ((const float4*)Wfc)[lane];
  h2 p0 = __builtin_bit_cast(h2, hv.x);
  h2 p1 = __builtin_bit_cast(h2, hv.y);
  float s = (float)p0.x * w.x + (float)p0.y * w.y +
            (float)p1.x * w.z + (float)p1.y * w.w;
#pragma unroll
  for (int m = 32; m; m >>= 1) s += __shfl_xor(s, m, 64);
  if (lane == 0) y[gw] = s + bfc[0];
}

extern "C" void kernel_launch(void* const* d_in, const int* in_sizes, int n_in,
                              void* d_out, int out_size, void* d_ws, size_t ws_size,
                              hipStream_t stream)
{
  const float* x   = (const float*)d_in[0];
  const float* Wih = (const float*)d_in[1];
  const float* Whh = (const float*)d_in[2];
  const float* bih = (const float*)d_in[3];
  const float* bhh = (const float*)d_in[4];
  const float* Wfc = (const float*)d_in[5];
  const float* bfc = (const float*)d_in[6];
  float* out      = (float*)d_out;
  __half* hist    = (__half*)d_ws;   // needs 64*2048*256*2 = 64 MiB

  (void)in_sizes; (void)n_in; (void)out_size; (void)ws_size;

  const int ldsBytes = 512 * PADW * 4 + 256 * 4 + 256 * 4;  // 108544
  hipFuncSetAttribute((const void*)lstm_main,
                      hipFuncAttributeMaxDynamicSharedMemorySize, ldsBytes);
  lstm_main<<<dim3(NB), dim3(512), ldsBytes, stream>>>(x, Wih, Whh, bih, bhh, out, hist);
  lstm_head<<<dim3((NB * SEQT) / 4), dim3(256), 0, stream>>>(hist, Wfc, bfc, out);
}